// Round 14
// baseline (16.244 us; speedup 1.0000x reference)
//
#include <hip/hip_runtime.h>

// Euler characteristic curve of sublevel cubical complex.
// x: [B,C,H,W] f32 -> out: [B,C,RES] f32.
//
// R9 scaffold + lower-star inner loop (1 ds_add/vertex, was 4), with R10's
// failure modes removed:
//   - ownership (R3-hardware-verified exact): cell owner = largest-index
//     maximizing vertex; smaller-index neighbors compare <=, larger-index <.
//     w = 1 - #edges_owned + #faces_owned, ONE atomic at bin(x_v).
//   - loads: just 6 float4 (rows r0-1..r0+4, clamped); ALL left/right halos
//     via __shfl(+-1) from neighbor lanes (12 bpermute << 48 saved ds_adds;
//     wrap-garbage lanes are exactly the image-boundary-masked ones).
//   - hist[bin][col] int32 x 32 cols (8 KiB); rotated conflict-free reduce;
//     kernel 2: sum 4 slice partials + 64-lane shfl scan -> out.
//   - launch_bounds(256,5) (VGPR cap 102).

#define BB 32
#define CC 16
#define HH 128
#define WW 128
#define RESB 64
#define NT 256
#define S 4
#define ROWS (HH / S)    // 32 rows per slice
#define RPT 4            // rows per thread
#define BC (BB * CC)

__device__ __forceinline__ int binq(float F) {
    // F in [0,1): ceil(F*63) lands in [0,63] -- no clamps needed.
    return (int)ceilf(F * 63.0f);
}

__global__ __launch_bounds__(NT, 5) void ecc_hist(const float* __restrict__ X,
                                                  int* __restrict__ ws) {
    __shared__ int hist[RESB * 32];  // [bin][col], 8 KiB
    const int blk = blockIdx.x;
    const int sl = blk & (S - 1);
    const int bc = blk >> 2;  // blk / S
    const int tid = threadIdx.x;
    const int ln = tid & 31;   // lane column
    const int lane = tid & 63; // wave lane
    const float* __restrict__ x = X + (size_t)bc * (HH * WW);

    {
        int4* h4 = (int4*)hist;
        h4[tid] = make_int4(0, 0, 0, 0);
        h4[tid + NT] = make_int4(0, 0, 0, 0);
    }
    __syncthreads();

    const int col4 = tid & 31;   // which float4 of the row
    const int tr = tid >> 5;     // 0..7 thread-row group
    const int r0 = sl * ROWS + tr * RPT;
    const int c0 = col4 * 4;
    const int rm1 = (r0 > 0) ? r0 - 1 : 0;            // up halo row (masked)
    const int rp4 = (r0 + 4 < HH) ? r0 + 4 : HH - 1;  // down halo row (masked)

    // 6 float4 loads, address-independent, hoisted.
    const float4 A0 = *(const float4*)(x + rm1 * WW + c0);
    const float4 A1 = *(const float4*)(x + (r0 + 0) * WW + c0);
    const float4 A2 = *(const float4*)(x + (r0 + 1) * WW + c0);
    const float4 A3 = *(const float4*)(x + (r0 + 2) * WW + c0);
    const float4 A4 = *(const float4*)(x + (r0 + 3) * WW + c0);
    const float4 A5 = *(const float4*)(x + rp4 * WW + c0);

    // Halos via wave shuffles (ds_bpermute): left = lane-1's .w, right = lane+1's .x.
    // Garbage at half-wave/image edges is exactly the hl0/hr3-masked lanes.
    float F[6][6];
#define SETROW(j, A)                                                     \
    F[j][0] = __shfl((A).w, lane - 1, 64);                               \
    F[j][1] = (A).x; F[j][2] = (A).y; F[j][3] = (A).z; F[j][4] = (A).w;  \
    F[j][5] = __shfl((A).x, lane + 1, 64);
    SETROW(0, A0) SETROW(1, A1) SETROW(2, A2) SETROW(3, A3) SETROW(4, A4) SETROW(5, A5)
#undef SETROW

    const int hl0 = (col4 > 0) ? 1 : 0;         // k==0 left neighbor exists
    const int hr3 = (col4 < 31) ? 1 : 0;        // k==3 right neighbor exists
    const int hU0 = (r0 > 0) ? 1 : 0;           // dr==0 up row exists
    const int hD3 = (r0 + 3 < HH - 1) ? 1 : 0;  // dr==3 down row exists

#pragma unroll
    for (int dr = 0; dr < RPT; ++dr) {
        const int hU = (dr > 0) ? 1 : hU0;  // folds to 1 for dr>0
        const int hD = (dr < 3) ? 1 : hD3;  // folds to 1 for dr<3
#pragma unroll
        for (int k = 0; k < 4; ++k) {
            const int hl = (k > 0) ? 1 : hl0;   // folds for k>0
            const int hr = (k < 3) ? 1 : hr3;   // folds for k<3
            const float xv = F[dr + 1][k + 1];
            // ownership predicates (smaller-index: <=, larger-index: <)
            const int pL = hl & (F[dr + 1][k] <= xv ? 1 : 0);
            const int pR = hr & (F[dr + 1][k + 2] < xv ? 1 : 0);
            const int pU = hU & (F[dr][k + 1] <= xv ? 1 : 0);
            const int pD = hD & (F[dr + 2][k + 1] < xv ? 1 : 0);
            const int w = 1 - pL - pR - pU - pD
                + (pU & pL & (F[dr][k] <= xv ? 1 : 0))
                + (pU & pR & (F[dr][k + 2] <= xv ? 1 : 0))
                + (pD & pL & (F[dr + 2][k] < xv ? 1 : 0))
                + (pD & pR & (F[dr + 2][k + 2] < xv ? 1 : 0));
            atomicAdd(&hist[(binq(xv) << 5) + ln], w);  // ONE ds_add / vertex
        }
    }
    __syncthreads();

    // Reduce over 32 columns: thread (bin = tid&63, q = tid>>6) sums 8,
    // full rotation -> 64 lanes cover all 32 banks (2-way = free).
    const int bin = tid & 63;
    const int q = tid >> 6;
    int ssum = 0;
#pragma unroll
    for (int k = 0; k < 8; ++k) {
        ssum += hist[(bin << 5) + ((q * 8 + bin + k) & 31)];
    }
    __syncthreads();
    hist[tid] = ssum;  // partial at [q*64 + bin]
    __syncthreads();
    if (tid < RESB) {
        ws[blk * RESB + tid] = hist[tid] + hist[tid + 64] + hist[tid + 128] + hist[tid + 192];
    }
}

__global__ __launch_bounds__(64) void ecc_scan(const int* __restrict__ ws,
                                               float* __restrict__ out) {
    const int bc = blockIdx.x;
    const int b = threadIdx.x;  // bin
    int v = 0;
#pragma unroll
    for (int si = 0; si < S; ++si) v += ws[(bc * S + si) * RESB + b];
    // Inclusive prefix scan over 64 lanes (= 64 bins) -> cumsum.
#pragma unroll
    for (int d = 1; d < 64; d <<= 1) {
        const int up = __shfl_up(v, d, 64);
        if (b >= d) v += up;
    }
    out[bc * RESB + b] = (float)v;
}

extern "C" void kernel_launch(void* const* d_in, const int* in_sizes, int n_in,
                              void* d_out, int out_size, void* d_ws, size_t ws_size,
                              hipStream_t stream) {
    const float* x = (const float*)d_in[0];
    float* out = (float*)d_out;
    int* ws = (int*)d_ws;  // BC*S*RESB ints = 512 KiB
    ecc_hist<<<BC * S, NT, 0, stream>>>(x, ws);
    ecc_scan<<<BC, 64, 0, stream>>>(ws, out);
}

// Round 15
// 14.542 us; speedup vs baseline: 1.1170x; 1.1170x over previous
//
#include <hip/hip_runtime.h>

// Euler characteristic curve of sublevel cubical complex.
// x: [B,C,H,W] f32 -> out: [B,C,RES] f32.
//
// R9 inner loop (proven best), single change: S=4 -> S=2 (halve block count).
//   Per-CU main-loop work unchanged; per-block fixed costs (8KiB hist
//   zero-init, epilogue reduce + barriers, ws write) halve -- R9 measured
//   the epilogue-LDS lever at ~-1us for a 2x cut. Scan kernel reads halve.
//   - per (image, 64-row slice) block; RPT=8 rows/thread, rolling 2-row
//     window (R4-proven; compiler free to hoist under full unroll).
//   - branchless 4-atomic per vertex into hist[bin][col] int32 x 32 cols
//     (8 KiB LDS; ds_add fire-and-forget; 2 lanes/bank = free aliasing);
//     edge/face bins via integer max (bin monotone: bin(max)=max(bin)).
//   - rotated conflict-free epilogue reduce; kernel 2: sum 2 partials +
//     64-lane shfl inclusive scan -> out.
//   - launch_bounds(256,5): VGPR cap 102.

#define BB 32
#define CC 16
#define HH 128
#define WW 128
#define RESB 64
#define NT 256
#define S 2
#define ROWS (HH / S)    // 64 rows per slice
#define RPT 8            // rows per thread (rolling)
#define BC (BB * CC)

__device__ __forceinline__ int binq(float F) {
    // F in [0,1): ceil(F*63) lands in [0,63] -- no clamps needed.
    return (int)ceilf(F * 63.0f);
}

__global__ __launch_bounds__(NT, 5) void ecc_hist(const float* __restrict__ X,
                                                  int* __restrict__ ws) {
    __shared__ int hist[RESB * 32];  // [bin][col], 8 KiB
    const int blk = blockIdx.x;
    const int sl = blk & (S - 1);
    const int bc = blk >> 1;  // blk / S
    const int tid = threadIdx.x;
    const int ln = tid & 31;  // lane column
    const float* __restrict__ x = X + (size_t)bc * (HH * WW);

    {
        int4* h4 = (int4*)hist;
        h4[tid] = make_int4(0, 0, 0, 0);
        h4[tid + NT] = make_int4(0, 0, 0, 0);
    }
    __syncthreads();

    const int col4 = tid & 31;   // which float4 of the row
    const int tr = tid >> 5;     // 0..7 thread-row group
    const int r0 = sl * ROWS + tr * RPT;
    const int c0 = col4 * 4;
    const int cR = (col4 < 31) ? c0 + 4 : WW - 1;  // right halo col (k=3 masked)

    int u[5], v[5];
    {
        const float4 a = *(const float4*)(x + r0 * WW + c0);
        const float aR = x[r0 * WW + cR];
        u[0] = binq(a.x); u[1] = binq(a.y); u[2] = binq(a.z); u[3] = binq(a.w); u[4] = binq(aR);
    }

    // Only the last owned row (r0+7, max 127) can touch the image boundary.
    const int hD7 = (r0 + RPT - 1 < HH - 1) ? 1 : 0;

#pragma unroll
    for (int dr = 0; dr < RPT; ++dr) {
        const int hD = (dr < RPT - 1) ? 1 : hD7;  // folds to 1 for dr<7
        const int r1 = (dr < RPT - 1) ? (r0 + dr + 1)
                                      : ((r0 + RPT < HH) ? r0 + RPT : HH - 1);
        {
            const float4 b = *(const float4*)(x + r1 * WW + c0);
            const float bR = x[r1 * WW + cR];
            v[0] = binq(b.x); v[1] = binq(b.y); v[2] = binq(b.z); v[3] = binq(b.w); v[4] = binq(bR);
        }
#pragma unroll
        for (int k = 0; k < 4; ++k) {
            const int hR = (k < 3) ? 1 : ((col4 < 31) ? 1 : 0);  // folds for k<3
            const int u00 = u[k];
            const int bh  = max(u00, u[k + 1]);
            const int bvv = max(u00, v[k]);
            const int bf  = max(bh, max(v[k], v[k + 1]));
            atomicAdd(&hist[(u00 << 5) + ln], 1);          // vertex +
            atomicAdd(&hist[(bh  << 5) + ln], -hR);        // h-edge -
            atomicAdd(&hist[(bvv << 5) + ln], -hD);        // v-edge -
            atomicAdd(&hist[(bf  << 5) + ln], hR & hD);    // face  +
        }
#pragma unroll
        for (int k = 0; k < 5; ++k) u[k] = v[k];
    }
    __syncthreads();

    // Reduce over 32 columns: thread (bin = tid&63, q = tid>>6) sums 8,
    // full rotation -> 64 lanes cover all 32 banks (2-way = free).
    const int bin = tid & 63;
    const int q = tid >> 6;
    int ssum = 0;
#pragma unroll
    for (int k = 0; k < 8; ++k) {
        ssum += hist[(bin << 5) + ((q * 8 + bin + k) & 31)];
    }
    __syncthreads();
    hist[tid] = ssum;  // partial at [q*64 + bin]
    __syncthreads();
    if (tid < RESB) {
        ws[blk * RESB + tid] = hist[tid] + hist[tid + 64] + hist[tid + 128] + hist[tid + 192];
    }
}

__global__ __launch_bounds__(64) void ecc_scan(const int* __restrict__ ws,
                                               float* __restrict__ out) {
    const int bc = blockIdx.x;
    const int b = threadIdx.x;  // bin
    int v = ws[(bc * S + 0) * RESB + b] + ws[(bc * S + 1) * RESB + b];
    // Inclusive prefix scan over 64 lanes (= 64 bins) -> cumsum.
#pragma unroll
    for (int d = 1; d < 64; d <<= 1) {
        const int up = __shfl_up(v, d, 64);
        if (b >= d) v += up;
    }
    out[bc * RESB + b] = (float)v;
}

extern "C" void kernel_launch(void* const* d_in, const int* in_sizes, int n_in,
                              void* d_out, int out_size, void* d_ws, size_t ws_size,
                              hipStream_t stream) {
    const float* x = (const float*)d_in[0];
    float* out = (float*)d_out;
    int* ws = (int*)d_ws;  // BC*S*RESB ints = 256 KiB
    ecc_hist<<<BC * S, NT, 0, stream>>>(x, ws);
    ecc_scan<<<BC, 64, 0, stream>>>(ws, out);
}

// Round 16
// 11.608 us; speedup vs baseline: 1.3994x; 1.2528x over previous
//
#include <hip/hip_runtime.h>

// Euler characteristic curve of sublevel cubical complex.
// x: [B,C,H,W] f32 -> out: [B,C,RES] f32.
//
// SINGLE-KERNEL S=1: one 512-thread block per image. Kills the scan kernel,
// the inter-kernel gap, and the ws round-trip (R7/R11 showed memset-node and
// counter-based fusions both lose; in-block completion needs neither).
//   - R9-proven inner loop: branchless 4 ds_add per vertex into
//     hist[bin][col] int32 x 32 cols (8 KiB; 2 lanes/bank = free aliasing);
//     edge/face bins via integer max (bin monotone: bin(max)=max(bin)).
//   - 8 rows/thread, depth-1 software pipeline: prefetch row r+2 before
//     computing row r (load lands under compute), bin-convert post-compute.
//   - epilogue: 512-thread rotated conflict-free reduce (4 sums/thread),
//     64-lane shfl inclusive scan, direct store to out.
//   - launch_bounds(512,6): VGPR cap 85 (est. live ~60-75, no spill),
//     2 blocks/CU = 16 waves/CU (R12: waves beyond ~20 were neutral).

#define HH 128
#define WW 128
#define RESB 64
#define NT 512
#define RPT 8            // rows per thread
#define BC 512           // one block per image

__device__ __forceinline__ int binq(float F) {
    // F in [0,1): ceil(F*63) lands in [0,63] -- no clamps needed.
    return (int)ceilf(F * 63.0f);
}

__global__ __launch_bounds__(NT, 6) void ecc_fused(const float* __restrict__ X,
                                                   float* __restrict__ out) {
    __shared__ int hist[RESB * 32];  // [bin][col], 8 KiB
    const int bc = blockIdx.x;
    const int tid = threadIdx.x;
    const int ln = tid & 31;  // lane column
    const float* __restrict__ x = X + (size_t)bc * (HH * WW);

    ((int4*)hist)[tid] = make_int4(0, 0, 0, 0);  // 2048 dwords / 512 threads
    __syncthreads();

    const int col4 = tid & 31;   // which float4 of the row
    const int rg = tid >> 5;     // 0..15 row group
    const int r0 = rg * RPT;
    const int c0 = col4 * 4;
    const int cR = (col4 < 31) ? c0 + 4 : WW - 1;  // right halo col (k=3 masked)

    int u[5], v[5], w[5];
    {
        const float4 a = *(const float4*)(x + r0 * WW + c0);
        const float aR = x[r0 * WW + cR];
        u[0] = binq(a.x); u[1] = binq(a.y); u[2] = binq(a.z); u[3] = binq(a.w); u[4] = binq(aR);
        const float4 b = *(const float4*)(x + (r0 + 1) * WW + c0);
        const float bR = x[(r0 + 1) * WW + cR];
        v[0] = binq(b.x); v[1] = binq(b.y); v[2] = binq(b.z); v[3] = binq(b.w); v[4] = binq(bR);
    }

#pragma unroll
    for (int dr = 0; dr < RPT; ++dr) {
        // hD folds to 1 for dr<7; last thread-row (rg=15, row 127) masked.
        const int hD = (dr < RPT - 1) ? 1 : ((rg < 15) ? 1 : 0);
        // Prefetch row r0+dr+2 (clamped) BEFORE compute -> load lands under it.
        float4 p4; float pR;
        if (dr < RPT - 1) {
            const int rn = (r0 + dr + 2 < HH) ? r0 + dr + 2 : HH - 1;
            p4 = *(const float4*)(x + rn * WW + c0);
            pR = x[rn * WW + cR];
        }
#pragma unroll
        for (int k = 0; k < 4; ++k) {
            const int hR = (k < 3) ? 1 : ((col4 < 31) ? 1 : 0);  // folds for k<3
            const int u00 = u[k];
            const int bh  = max(u00, u[k + 1]);
            const int bvv = max(u00, v[k]);
            const int bf  = max(bh, max(v[k], v[k + 1]));
            atomicAdd(&hist[(u00 << 5) + ln], 1);          // vertex +
            atomicAdd(&hist[(bh  << 5) + ln], -hR);        // h-edge -
            atomicAdd(&hist[(bvv << 5) + ln], -hD);        // v-edge -
            atomicAdd(&hist[(bf  << 5) + ln], hR & hD);    // face  +
        }
        if (dr < RPT - 1) {
            w[0] = binq(p4.x); w[1] = binq(p4.y); w[2] = binq(p4.z); w[3] = binq(p4.w); w[4] = binq(pR);
#pragma unroll
            for (int k = 0; k < 5; ++k) { u[k] = v[k]; v[k] = w[k]; }
        }
    }
    __syncthreads();

    // Reduce over 32 columns: thread (bin = tid&63, q = tid>>6 in 0..7) sums 4,
    // rotated -> all 32 banks covered, 2 lanes/bank = free.
    const int bin = tid & 63;
    const int q = tid >> 6;
    int ssum = 0;
#pragma unroll
    for (int k = 0; k < 4; ++k) {
        ssum += hist[(bin << 5) + ((q * 4 + bin + k) & 31)];
    }
    __syncthreads();
    hist[tid] = ssum;  // partial at [q*64 + bin]
    __syncthreads();
    if (tid < RESB) {
        int vv = 0;
#pragma unroll
        for (int qq = 0; qq < 8; ++qq) vv += hist[qq * 64 + tid];
        // Inclusive prefix scan across 64 lanes (= bins) -> cumsum.
#pragma unroll
        for (int d = 1; d < 64; d <<= 1) {
            const int up = __shfl_up(vv, d, 64);
            if (tid >= d) vv += up;
        }
        out[bc * RESB + tid] = (float)vv;
    }
}

extern "C" void kernel_launch(void* const* d_in, const int* in_sizes, int n_in,
                              void* d_out, int out_size, void* d_ws, size_t ws_size,
                              hipStream_t stream) {
    const float* x = (const float*)d_in[0];
    float* out = (float*)d_out;
    ecc_fused<<<BC, NT, 0, stream>>>(x, out);
}